// Round 3
// baseline (78.638 us; speedup 1.0000x reference)
//
#include <hip/hip_runtime.h>
#include <math.h>

#define BATCH 2
#define NPTS  1024
#define NC    32
#define DIN   8
#define DOUT  8
#define ATILE 64                          // a's per block (4 waves x 16)
#define NCHUNK 32                         // b-splits
#define BPW   (NPTS / NCHUNK)             // 32 b's per block
#define OUT_ELEMS (BATCH * NPTS * DOUT)   // 16384
#define LOG2E 1.4426950408889634f

typedef _Float16 half8 __attribute__((ext_vector_type(8)));
typedef __fp16   fp16x2 __attribute__((ext_vector_type(2)));
typedef float    floatx4 __attribute__((ext_vector_type(4)));

#if __has_builtin(__builtin_amdgcn_exp2f)
#define EXP2F(x) __builtin_amdgcn_exp2f(x)
#else
#define EXP2F(x) exp2f(x)
#endif

// ---------------------------------------------------------------------------
// conv_fused v7 — attack the LAST structural cost (R14 post-mortem: removing
// one dispatch + round-trip saved 2.7us while three inner-loop fixes were
// null => per-node cost + round-trips, not the loop, are the addressable
// time besides the fixed 40us ws-poison fill).
// Changes vs v6 (inner-loop math and LDS bytes identical):
//  * g_kernel folded into conv prologue: each block builds its own 32KB
//    G-tile in LDS straight from feat/W (65K fmaf/block, ~0.2us), killing
//    the g dispatch, the gws 2MB write and the 32MB L2 re-read. d_ws unused.
//  * out zero-init via hipMemsetAsync node (64KB) so the atomic epilogue
//    stays (32 adds/address, overlapped with compute).
// G bytes provably identical to g_kernel: same slot layout (slot=oct*16+i,
// i<8; slot&8 half zeroed), same fmaf reduction order, same (s*scale) f16
// quantization point => absmax unchanged.
// Exp recurrence unchanged (R12-verified numerics; NaN/underflow proof:
// upper clamp tc<=11 keeps 0*finite=0; chains <=3 muls from each seed).
// ---------------------------------------------------------------------------
__global__ __launch_bounds__(256, 4) void conv_fused(
        const float* __restrict__ feat,
        const float* __restrict__ geo,
        const float* __restrict__ W,
        const int*   __restrict__ n_norm,
        float*       __restrict__ out) {   // [BATCH*NPTS][DOUT], pre-zeroed
    const int t     = threadIdx.x;
    const int bid   = blockIdx.x;
    const int chunk = bid & (NCHUNK - 1);
    const int atile = (bid >> 5) & 15;
    const int z     = bid >> 9;

    const int b0 = chunk * BPW;
    const float* geoz = geo + (size_t)z * NPTS * 3;
    const float* bge  = geoz + b0 * 3;         // wave-uniform base

    // ---- build this chunk's G-tile in LDS: 32 b x 64 slots x 16B = 32KB ----
    // Thread t owns slot = t&63 for 8 b's: b = k*4 + (t>>6), k=0..7.
    __shared__ half8 ldsG[BPW * 64];
    {
        const int slot = t & 63;
        const int bgrp = t >> 6;
        if (!(slot & 8)) {
            const int i   = slot & 7;
            const int oct = slot >> 4;
            const float scale = 1.0f / sqrtf((float)n_norm[0]);
            // hoist the slot's 8 W rows (shared across its 8 b's)
            float4 wa[8], wb[8];
#pragma unroll
            for (int j = 0; j < 8; ++j) {
                const float* wr = W + ((oct * 8 + j) * DOUT + i) * DIN;
                wa[j] = *(const float4*)wr;
                wb[j] = *(const float4*)(wr + 4);
            }
            const float* featz = feat + ((size_t)z * NPTS + b0) * DIN;
#pragma unroll
            for (int k = 0; k < 8; ++k) {
                const int b = k * 4 + bgrp;
                const float4 f0 = *(const float4*)(featz + b * DIN);
                const float4 f1 = *(const float4*)(featz + b * DIN + 4);
                half8 gv;
#pragma unroll
                for (int j = 0; j < 8; ++j) {
                    float s = fmaf(wa[j].x, f0.x,
                              fmaf(wa[j].y, f0.y,
                              fmaf(wa[j].z, f0.z,
                              fmaf(wa[j].w, f0.w,
                              fmaf(wb[j].x, f1.x,
                              fmaf(wb[j].y, f1.y,
                              fmaf(wb[j].z, f1.z,
                                     wb[j].w * f1.w)))))));
                    gv[j] = (_Float16)(s * scale);
                }
                ldsG[b * 64 + slot] = gv;
            }
        } else {
            const half8 zv = {};
#pragma unroll
            for (int k = 0; k < 8; ++k)
                ldsG[(k * 4 + bgrp) * 64 + slot] = zv;
        }
    }

    const int lane = t & 63;
    const int wv   = t >> 6;
    const int m    = lane & 15;
    const int quad = lane >> 4;
    const int a0   = atile * ATILE + wv * 16;
    const int a    = a0 + m;

    const float ax = geoz[a * 3 + 0];
    const float ay = geoz[a * 3 + 1];
    const float az = geoz[a * 3 + 2];
    const float c0   = (float)(quad * 8);
    const float invw = (float)(NC - 1) / 3.5f;
    const float K2   = 0.13533528324f;         // exp(-2)
    const float K8   = 3.35462627903e-4f;      // exp(-8)

    floatx4 acc0 = {0.f, 0.f, 0.f, 0.f};
    floatx4 acc1 = {0.f, 0.f, 0.f, 0.f};

    __syncthreads();

#pragma unroll 4
    for (int b = 0; b < BPW; ++b) {
        // wave-uniform geo (uniform address -> s_load)
        const float bx = bge[b * 3 + 0];
        const float by = bge[b * 3 + 1];
        const float bz = bge[b * 3 + 2];
        const float dx = bx - ax, dy = by - ay, dz = bz - az;
        const float u  = sqrtf(fmaf(dx, dx, fmaf(dy, dy, fmaf(dz, dz, 1e-12f)))) * invw;
        const float tc = fminf(u - c0, 11.0f);
        // seeds + ratios
        const float e0 = EXP2F((tc * tc) * (-LOG2E));
        const float t4 = tc - 4.0f;
        const float e4 = EXP2F((t4 * t4) * (-LOG2E));
        const float r0 = EXP2F(fmaf(2.0f * LOG2E, tc, -LOG2E));   // exp(2tc-1)
        const float r4 = r0 * K8;                                  // exp(2t4-1)
        // chains (<=3 muls from each seed)
        const float e1 = e0 * r0;  const float r1 = r0 * K2;
        const float e2 = e1 * r1;  const float r2 = r1 * K2;
        const float e3 = e2 * r2;
        const float e5 = e4 * r4;  const float r5 = r4 * K2;
        const float e6 = e5 * r5;  const float r6 = r5 * K2;
        const float e7 = e6 * r6;
        union { half8 v; fp16x2 h[4]; } af;
        af.h[0] = __builtin_amdgcn_cvt_pkrtz(e0, e1);
        af.h[1] = __builtin_amdgcn_cvt_pkrtz(e2, e3);
        af.h[2] = __builtin_amdgcn_cvt_pkrtz(e4, e5);
        af.h[3] = __builtin_amdgcn_cvt_pkrtz(e6, e7);
        const half8 bfrg = ldsG[b * 64 + lane];    // ds_read_b128, conflict-free
        if (b & 1)
            acc1 = __builtin_amdgcn_mfma_f32_16x16x32_f16(af.v, bfrg, acc1, 0, 0, 0);
        else
            acc0 = __builtin_amdgcn_mfma_f32_16x16x32_f16(af.v, bfrg, acc0, 0, 0, 0);
    }

    // ---- epilogue: D col = i (lane&15, keep <8), row = quad*4 + reg ----
    if (m < 8) {
        float* pp = out + ((size_t)(z * NPTS + a0 + quad * 4)) * DOUT + m;
#pragma unroll
        for (int r = 0; r < 4; ++r)
            atomicAdd(pp + r * DOUT, acc0[r] + acc1[r]);
    }
}

// ---------------------------------------------------------------------------
extern "C" void kernel_launch(void* const* d_in, const int* in_sizes, int n_in,
                              void* d_out, int out_size, void* d_ws, size_t ws_size,
                              hipStream_t stream) {
    const float* feat   = (const float*)d_in[0];   // [2,1024,8]
    const float* geo    = (const float*)d_in[1];   // [2,1024,3]
    const float* W      = (const float*)d_in[2];   // [32,8,8]
    const int*   n_norm = (const int*)  d_in[3];   // scalar 1024
    float* out = (float*)d_out;                    // [2,1024,8]

    (void)d_ws; (void)ws_size;

    hipMemsetAsync(out, 0, (size_t)OUT_ELEMS * sizeof(float), stream);
    conv_fused<<<BATCH * 16 * NCHUNK, 256, 0, stream>>>(feat, geo, W, n_norm, out);
}